// Round 12
// baseline (308.801 us; speedup 1.0000x reference)
//
#include <hip/hip_runtime.h>
#include <stdint.h>

#define NPTS 32768
#define KOFF 27
#define CH   128
#define NC   (NPTS*CH)
#define KSPLIT 3
#define KPG  9
#define TILE_M 64
#define NITER (KPG*2)      // 18 BK=64 steps per block
#define RBLK  256          // fused reduce kernels: 256 blocks x 128 rows

typedef __attribute__((ext_vector_type(8))) short short8;   // 8 bf16 (MFMA A/B frag)
typedef __attribute__((ext_vector_type(4))) float f32x4;    // MFMA C/D frag
typedef unsigned short u16;

__device__ __forceinline__ float bf2f(u16 u) {
    union { uint32_t i; float f; } v; v.i = ((uint32_t)u) << 16; return v.f;
}
__device__ __forceinline__ u16 f2bf(float f) {
    union { float f; uint32_t i; } v; v.f = f;
    return (u16)((v.i + 0x7FFF + ((v.i >> 16) & 1)) >> 16);  // RNE
}

#define GLDS16(gp, lp) __builtin_amdgcn_global_load_lds( \
    (__attribute__((address_space(1))) void*)(gp),           \
    (__attribute__((address_space(3))) void*)(lp), 16, 0, 0)

// ---------------------------------------------------------------------------
// prep (fused): b<54 -> W[k][c][d] fp32 -> Wt[k][d][c] bf16; block 0 zeros
// stats+counters; b>=54 -> feats fp32 -> bf16 (8 elems/thread)
// ---------------------------------------------------------------------------
__global__ __launch_bounds__(256)
void prep_kernel(const float* __restrict__ W1, const float* __restrict__ W2,
                 u16* __restrict__ W1t, u16* __restrict__ W2t,
                 const float* __restrict__ feats, u16* __restrict__ xbuf,
                 float* __restrict__ stat)
{
    __shared__ u16 t[128*129];
    const int b = blockIdx.x, tid = threadIdx.x;
    if (b < 2*KOFF) {
        if (b == 0) for (int i = tid; i < 640; i += 256) stat[i] = 0.0f;  // 512 stats + 2 ctrs + pad
        const float* src = (b < KOFF) ? W1 + (size_t)b*CH*CH : W2 + (size_t)(b-KOFF)*CH*CH;
        u16* dst         = (b < KOFF) ? W1t + (size_t)b*CH*CH : W2t + (size_t)(b-KOFF)*CH*CH;
        for (int e = tid; e < CH*CH; e += 256) {
            int c = e >> 7, d = e & 127;
            t[d*129 + c] = f2bf(src[e]);
        }
        __syncthreads();
        for (int e = tid; e < CH*CH; e += 256) {
            int d = e >> 7, c = e & 127;
            dst[e] = t[d*129 + c];
        }
    } else {
        size_t e = ((size_t)(b - 2*KOFF) * 256 + tid) * 8;
        float4 a = *(const float4*)(feats + e);
        float4 c = *(const float4*)(feats + e + 4);
        ushort4 lo, hi;
        lo.x = f2bf(a.x); lo.y = f2bf(a.y); lo.z = f2bf(a.z); lo.w = f2bf(a.w);
        hi.x = f2bf(c.x); hi.y = f2bf(c.y); hi.z = f2bf(c.z); hi.w = f2bf(c.w);
        *(ushort4*)(xbuf + e) = lo;
        *(ushort4*)(xbuf + e + 4) = hi;
    }
}

// ---------------------------------------------------------------------------
// gathered MFMA GEMM. Grid (512 M-tiles, 3 k-groups) = 1536 blocks; u16 idx
// + 25.1 KB LDS + __launch_bounds__(256,6) -> 6 blocks/CU = 24 waves/CU,
// whole grid co-resident. 64x128 tile, 4 waves each 32x64, 16x16x32 bf16
// MFMA, BK=64, GLDS16 staging with source-chunk XOR swizzle. bf16 partials.
// ---------------------------------------------------------------------------
__global__ __launch_bounds__(256, 6)
void ResidualBlock_77498389889548_kernel(const u16* __restrict__ xb,
                                         const int* __restrict__ nbr,
                                         const u16* __restrict__ Wt,
                                         u16* __restrict__ part)
{
    __shared__ __align__(16) u16 A_lds[TILE_M*64];   // 8 KB swizzled
    __shared__ __align__(16) u16 B_lds[CH*64];       // 16 KB swizzled
    __shared__ u16 idx_lds[KPG*TILE_M];              // 1.1 KB (indices < 32768)

    const int tid = threadIdx.x;
    const int n0  = blockIdx.x * TILE_M;
    const int kg  = blockIdx.y;

    for (int e = tid; e < KPG*TILE_M; e += 256) {
        int kk = e >> 6, r = e & 63;
        int nb = nbr[(size_t)(n0 + r)*KOFF + kg*KPG + kk];
        idx_lds[e] = (u16)(((unsigned)nb < (unsigned)NPTS) ? nb : 0);
    }
    __syncthreads();

    const int wave = tid >> 6;
    const int lane = tid & 63;
    const int wrow = (wave >> 1) * 32;
    const int wcol = (wave & 1) * 64;
    const int lm   = lane & 15;
    const int quad = lane >> 4;
    const int l8r  = lane >> 3;                        // row-in-8 for staging
    const int swz  = ((lane & 7) ^ l8r) << 3;          // source chunk (elements)

    f32x4 acc[2][4];
    #pragma unroll
    for (int i = 0; i < 2; ++i)
        #pragma unroll
        for (int j = 0; j < 4; ++j)
            #pragma unroll
            for (int r = 0; r < 4; ++r) acc[i][j][r] = 0.0f;

    int aoff[2][2], boff[2][4];
    #pragma unroll
    for (int kc = 0; kc < 2; ++kc) {
        int g = kc*4 + quad;
        #pragma unroll
        for (int i = 0; i < 2; ++i) {
            int row = wrow + i*16 + lm;
            aoff[kc][i] = row*128 + ((g ^ (row & 7)) << 4);
        }
        #pragma unroll
        for (int j = 0; j < 4; ++j) {
            int d = wcol + j*16 + lm;
            boff[kc][j] = d*128 + ((g ^ (d & 7)) << 4);
        }
    }

    const char* Ab = (const char*)A_lds;
    const char* Bb = (const char*)B_lds;

    for (int it = 0; it < NITER; ++it) {
        const int kk = it >> 1;
        const int h  = it & 1;

        // stage A (gather, 64 rows): 2 GLDS16/wave
        #pragma unroll
        for (int j = 0; j < 2; ++j) {
            int row8 = wave*16 + j*8;                  // wave-uniform
            int nb = (int)idx_lds[kk*64 + row8 + l8r];
            GLDS16(xb + (size_t)nb*CH + h*64 + swz, &A_lds[row8*64]);
        }
        // stage B (128 rows): 4 GLDS16/wave
        const u16* wb = Wt + (size_t)(kg*KPG + kk)*CH*CH + h*64 + swz;
        #pragma unroll
        for (int j = 0; j < 4; ++j) {
            int row8 = wave*32 + j*8;
            GLDS16(wb + (size_t)(row8 + l8r)*CH, &B_lds[row8*64]);
        }
        __syncthreads();   // drain staging loads

        #pragma unroll
        for (int kc = 0; kc < 2; ++kc) {
            short8 a[2], b[4];
            #pragma unroll
            for (int i = 0; i < 2; ++i) a[i] = *(const short8*)(Ab + aoff[kc][i]);
            #pragma unroll
            for (int j = 0; j < 4; ++j) b[j] = *(const short8*)(Bb + boff[kc][j]);
            #pragma unroll
            for (int i = 0; i < 2; ++i)
                #pragma unroll
                for (int j = 0; j < 4; ++j)
                    acc[i][j] = __builtin_amdgcn_mfma_f32_16x16x32_bf16(a[i], b[j], acc[i][j], 0, 0, 0);
        }
        __syncthreads();   // all reads done before next overwrite
    }

    // epilogue: C/D layout col=lane&15, row=quad*4+reg -> bf16 partial kg
    u16* pb = part + (size_t)kg * NC;
    const int colb = wcol + lm;
    #pragma unroll
    for (int i = 0; i < 2; ++i) {
        #pragma unroll
        for (int r = 0; r < 4; ++r) {
            int row = n0 + wrow + i*16 + quad*4 + r;
            u16* pp = pb + (size_t)row*CH + colb;
            #pragma unroll
            for (int j = 0; j < 4; ++j) pp[j*16] = f2bf(acc[i][j][r]);
        }
    }
}

// ---------------------------------------------------------------------------
// shared body for the fused reduce kernels: compute v = p0+p1+p2 for this
// block's 128-row slice (cached bf16 in LDS), exact channel stats -> global
// atomics, device-scope arrival counter + spin until all 256 blocks arrive.
// ---------------------------------------------------------------------------
#define FUSED_PROLOGUE(p0, p1, p2, gsum, gsq, ctr)                              \
    __shared__ u16 vbuf[128*CH];      /* 32 KB */                               \
    __shared__ float ls[CH], lq[CH];                                            \
    const int tid = threadIdx.x;                                                \
    const int b = blockIdx.x;                                                   \
    const int c8 = (tid & 15) * 8;                                              \
    const int r0 = tid >> 4;                                                    \
    if (tid < CH) { ls[tid] = 0.0f; lq[tid] = 0.0f; }                           \
    __syncthreads();                                                            \
    {                                                                           \
        float s[8], q[8];                                                       \
        _Pragma("unroll") for (int i = 0; i < 8; ++i) { s[i]=0.0f; q[i]=0.0f; } \
        for (int i = 0; i < 8; ++i) {                                           \
            int r = r0 + i*16;                                                  \
            size_t e = (size_t)(b*128 + r)*CH + c8;                             \
            ushort4 a0 = *(const ushort4*)(p0 + e), a1 = *(const ushort4*)(p0 + e + 4); \
            ushort4 b0 = *(const ushort4*)(p1 + e), b1 = *(const ushort4*)(p1 + e + 4); \
            ushort4 d0 = *(const ushort4*)(p2 + e), d1 = *(const ushort4*)(p2 + e + 4); \
            float v[8];                                                         \
            v[0]=bf2f(a0.x)+bf2f(b0.x)+bf2f(d0.x); v[1]=bf2f(a0.y)+bf2f(b0.y)+bf2f(d0.y); \
            v[2]=bf2f(a0.z)+bf2f(b0.z)+bf2f(d0.z); v[3]=bf2f(a0.w)+bf2f(b0.w)+bf2f(d0.w); \
            v[4]=bf2f(a1.x)+bf2f(b1.x)+bf2f(d1.x); v[5]=bf2f(a1.y)+bf2f(b1.y)+bf2f(d1.y); \
            v[6]=bf2f(a1.z)+bf2f(b1.z)+bf2f(d1.z); v[7]=bf2f(a1.w)+bf2f(b1.w)+bf2f(d1.w); \
            u16* vp = &vbuf[r*CH + c8];                                         \
            _Pragma("unroll") for (int j = 0; j < 8; ++j) vp[j] = f2bf(v[j]);   \
            _Pragma("unroll") for (int j = 0; j < 8; ++j) { s[j]+=v[j]; q[j]+=v[j]*v[j]; } \
        }                                                                       \
        _Pragma("unroll") for (int j = 0; j < 8; ++j) {                         \
            atomicAdd(&ls[c8 + j], s[j]); atomicAdd(&lq[c8 + j], q[j]);         \
        }                                                                       \
    }                                                                           \
    __syncthreads();                                                            \
    if (tid < CH) { atomicAdd(&gsum[tid], ls[tid]); atomicAdd(&gsq[tid], lq[tid]); } \
    __syncthreads();                                                            \
    if (tid == 0) {                                                             \
        __threadfence();                                                        \
        __hip_atomic_fetch_add(ctr, 1u, __ATOMIC_RELEASE, __HIP_MEMORY_SCOPE_AGENT); \
        while (__hip_atomic_load(ctr, __ATOMIC_ACQUIRE, __HIP_MEMORY_SCOPE_AGENT) < (unsigned)RBLK) \
            __builtin_amdgcn_s_sleep(8);                                        \
    }                                                                           \
    __syncthreads();                                                            \
    if (tid < CH) {                                                             \
        float su = __hip_atomic_load(&gsum[tid], __ATOMIC_RELAXED, __HIP_MEMORY_SCOPE_AGENT); \
        float sq = __hip_atomic_load(&gsq[tid],  __ATOMIC_RELAXED, __HIP_MEMORY_SCOPE_AGENT); \
        float mu  = su * (1.0f/NPTS);                                           \
        float var = fmaxf(sq * (1.0f/NPTS) - mu*mu, 0.0f);                      \
        float rs  = rsqrtf(var + 1e-5f);                                        \
        float sf  = rs * gam[tid];                                              \
        ls[tid] = sf; lq[tid] = bet[tid] - mu*sf;   /* sc, sh */                \
    }                                                                           \
    __syncthreads();

// fused1: xo(bf16) = relu(bn(p0+p1+p2; g,b))
__global__ __launch_bounds__(256)
void fused_norm_kernel(const u16* __restrict__ p0, const u16* __restrict__ p1,
                       const u16* __restrict__ p2,
                       float* __restrict__ gsum, float* __restrict__ gsq,
                       unsigned* __restrict__ ctr,
                       const float* __restrict__ gam, const float* __restrict__ bet,
                       u16* __restrict__ xo)
{
    FUSED_PROLOGUE(p0, p1, p2, gsum, gsq, ctr)
    for (int i = 0; i < 8; ++i) {
        int r = r0 + i*16;
        size_t e = (size_t)(b*128 + r)*CH + c8;
        const u16* vp = &vbuf[r*CH + c8];
        ushort4 o0, o1;
        o0.x = f2bf(fmaxf(bf2f(vp[0])*ls[c8+0] + lq[c8+0], 0.0f));
        o0.y = f2bf(fmaxf(bf2f(vp[1])*ls[c8+1] + lq[c8+1], 0.0f));
        o0.z = f2bf(fmaxf(bf2f(vp[2])*ls[c8+2] + lq[c8+2], 0.0f));
        o0.w = f2bf(fmaxf(bf2f(vp[3])*ls[c8+3] + lq[c8+3], 0.0f));
        o1.x = f2bf(fmaxf(bf2f(vp[4])*ls[c8+4] + lq[c8+4], 0.0f));
        o1.y = f2bf(fmaxf(bf2f(vp[5])*ls[c8+5] + lq[c8+5], 0.0f));
        o1.z = f2bf(fmaxf(bf2f(vp[6])*ls[c8+6] + lq[c8+6], 0.0f));
        o1.w = f2bf(fmaxf(bf2f(vp[7])*ls[c8+7] + lq[c8+7], 0.0f));
        *(ushort4*)(xo + e) = o0;
        *(ushort4*)(xo + e + 4) = o1;
    }
}

// fused2: out(fp32) = relu(bn(p0+p1+p2; g,b) + feats)
__global__ __launch_bounds__(256)
void fused_final_kernel(const u16* __restrict__ p0, const u16* __restrict__ p1,
                        const u16* __restrict__ p2,
                        float* __restrict__ gsum, float* __restrict__ gsq,
                        unsigned* __restrict__ ctr,
                        const float* __restrict__ gam, const float* __restrict__ bet,
                        const float* __restrict__ feats, float* __restrict__ out)
{
    FUSED_PROLOGUE(p0, p1, p2, gsum, gsq, ctr)
    for (int i = 0; i < 8; ++i) {
        int r = r0 + i*16;
        size_t e = (size_t)(b*128 + r)*CH + c8;
        const u16* vp = &vbuf[r*CH + c8];
        float4 f0 = *(const float4*)(feats + e);
        float4 f1 = *(const float4*)(feats + e + 4);
        float4 o0, o1;
        o0.x = fmaxf(bf2f(vp[0])*ls[c8+0] + lq[c8+0] + f0.x, 0.0f);
        o0.y = fmaxf(bf2f(vp[1])*ls[c8+1] + lq[c8+1] + f0.y, 0.0f);
        o0.z = fmaxf(bf2f(vp[2])*ls[c8+2] + lq[c8+2] + f0.z, 0.0f);
        o0.w = fmaxf(bf2f(vp[3])*ls[c8+3] + lq[c8+3] + f0.w, 0.0f);
        o1.x = fmaxf(bf2f(vp[4])*ls[c8+4] + lq[c8+4] + f1.x, 0.0f);
        o1.y = fmaxf(bf2f(vp[5])*ls[c8+5] + lq[c8+5] + f1.y, 0.0f);
        o1.z = fmaxf(bf2f(vp[6])*ls[c8+6] + lq[c8+6] + f1.z, 0.0f);
        o1.w = fmaxf(bf2f(vp[7])*ls[c8+7] + lq[c8+7] + f1.w, 0.0f);
        *(float4*)(out + e) = o0;
        *(float4*)(out + e + 4) = o1;
    }
}

// ---------------------------------------------------------------------------
extern "C" void kernel_launch(void* const* d_in, const int* in_sizes, int n_in,
                              void* d_out, int out_size, void* d_ws, size_t ws_size,
                              hipStream_t stream)
{
    const float* feats = (const float*)d_in[0];
    const int*   nbr   = (const int*)d_in[1];
    const float* W1    = (const float*)d_in[2];
    const float* g1    = (const float*)d_in[3];
    const float* b1    = (const float*)d_in[4];
    const float* W2    = (const float*)d_in[5];
    const float* g2    = (const float*)d_in[6];
    const float* b2    = (const float*)d_in[7];
    float* out = (float*)d_out;

    // ws (~37 MB): xbuf | prt0..2 (bf16) | Wt1 | Wt2 | stat[512]+ctrs
    char* ws = (char*)d_ws;
    u16*   xbuf = (u16*)ws;                                   // 8.4 MB
    u16*   prt  = xbuf + (size_t)NC;                          // 3 x 8.4 MB
    u16*   W1t  = prt + (size_t)3*NC;
    u16*   W2t  = W1t + (size_t)KOFF*CH*CH;
    float* stat = (float*)(W2t + (size_t)KOFF*CH*CH);         // s1,q1,s2,q2
    unsigned* ctrs = (unsigned*)(stat + 512);                 // ctr1, ctr2

    prep_kernel<<<dim3(2*KOFF + NC/2048), 256, 0, stream>>>(W1, W2, W1t, W2t, feats, xbuf, stat);

    ResidualBlock_77498389889548_kernel<<<dim3(NPTS/TILE_M, KSPLIT), 256, 0, stream>>>(
        xbuf, nbr, W1t, prt);
    fused_norm_kernel<<<dim3(RBLK), 256, 0, stream>>>(
        prt, prt + (size_t)NC, prt + (size_t)2*NC, stat, stat + 128, ctrs, g1, b1, xbuf);

    ResidualBlock_77498389889548_kernel<<<dim3(NPTS/TILE_M, KSPLIT), 256, 0, stream>>>(
        xbuf, nbr, W2t, prt);
    fused_final_kernel<<<dim3(RBLK), 256, 0, stream>>>(
        prt, prt + (size_t)NC, prt + (size_t)2*NC, stat + 256, stat + 384, ctrs + 1, g2, b2, feats, out);
}

// Round 13
// 215.141 us; speedup vs baseline: 1.4353x; 1.4353x over previous
//
#include <hip/hip_runtime.h>
#include <stdint.h>

#define NPTS 32768
#define KOFF 27
#define CH   128
#define NC   (NPTS*CH)
#define KSPLIT 3
#define KPG  9
#define TILE_M 64
#define NITER (KPG*2)      // 18 BK=64 steps per block

typedef __attribute__((ext_vector_type(8))) short short8;   // 8 bf16 (MFMA A/B frag)
typedef __attribute__((ext_vector_type(4))) float f32x4;    // MFMA C/D frag
typedef unsigned short u16;

__device__ __forceinline__ float bf2f(u16 u) {
    union { uint32_t i; float f; } v; v.i = ((uint32_t)u) << 16; return v.f;
}
__device__ __forceinline__ u16 f2bf(float f) {
    union { float f; uint32_t i; } v; v.f = f;
    return (u16)((v.i + 0x7FFF + ((v.i >> 16) & 1)) >> 16);  // RNE
}

#define GLDS16(gp, lp) __builtin_amdgcn_global_load_lds( \
    (__attribute__((address_space(1))) void*)(gp),           \
    (__attribute__((address_space(3))) void*)(lp), 16, 0, 0)

// ---------------------------------------------------------------------------
// prep (fused): b<54 -> W[k][c][d] fp32 -> Wt[k][d][c] bf16; block 0 zeros
// stats; b>=54 -> feats fp32 -> bf16 (8 elems/thread)
// ---------------------------------------------------------------------------
__global__ __launch_bounds__(256)
void prep_kernel(const float* __restrict__ W1, const float* __restrict__ W2,
                 u16* __restrict__ W1t, u16* __restrict__ W2t,
                 const float* __restrict__ feats, u16* __restrict__ xbuf,
                 float* __restrict__ stat)
{
    __shared__ u16 t[128*129];
    const int b = blockIdx.x, tid = threadIdx.x;
    if (b < 2*KOFF) {
        if (b == 0) for (int i = tid; i < 512; i += 256) stat[i] = 0.0f;
        const float* src = (b < KOFF) ? W1 + (size_t)b*CH*CH : W2 + (size_t)(b-KOFF)*CH*CH;
        u16* dst         = (b < KOFF) ? W1t + (size_t)b*CH*CH : W2t + (size_t)(b-KOFF)*CH*CH;
        for (int e = tid; e < CH*CH; e += 256) {
            int c = e >> 7, d = e & 127;
            t[d*129 + c] = f2bf(src[e]);
        }
        __syncthreads();
        for (int e = tid; e < CH*CH; e += 256) {
            int d = e >> 7, c = e & 127;
            dst[e] = t[d*129 + c];
        }
    } else {
        size_t e = ((size_t)(b - 2*KOFF) * 256 + tid) * 8;
        float4 a = *(const float4*)(feats + e);
        float4 c = *(const float4*)(feats + e + 4);
        ushort4 lo, hi;
        lo.x = f2bf(a.x); lo.y = f2bf(a.y); lo.z = f2bf(a.z); lo.w = f2bf(a.w);
        hi.x = f2bf(c.x); hi.y = f2bf(c.y); hi.z = f2bf(c.z); hi.w = f2bf(c.w);
        *(ushort4*)(xbuf + e) = lo;
        *(ushort4*)(xbuf + e + 4) = hi;
    }
}

// ---------------------------------------------------------------------------
// gathered MFMA GEMM. Grid (512 M-tiles, 3 k-groups) = 1536 blocks;
// __launch_bounds__(256,5) + 27.1 KB LDS -> 5 co-resident blocks/CU
// (r11-proven optimum; 6/CU regressed via write-side L2 thrash, r12).
// 64x128 tile, 4 waves each 32x64, 16x16x32 bf16 MFMA, BK=64, GLDS16
// staging with source-chunk XOR swizzle. K-loop runs h (row half) OUTER:
// all blocks gather bytes [0,64) of every row first, then [64,128) --
// halves the instantaneous gather working set (8.4 -> 4.2 MB ~ per-XCD L2).
// ---------------------------------------------------------------------------
__global__ __launch_bounds__(256, 5)
void ResidualBlock_77498389889548_kernel(const u16* __restrict__ xb,
                                         const int* __restrict__ nbr,
                                         const u16* __restrict__ Wt,
                                         u16* __restrict__ part)
{
    __shared__ __align__(16) u16 A_lds[TILE_M*64];   // 8 KB swizzled
    __shared__ __align__(16) u16 B_lds[CH*64];       // 16 KB swizzled
    __shared__ int idx_lds[KPG*TILE_M];              // 2.3 KB

    const int tid = threadIdx.x;
    const int n0  = blockIdx.x * TILE_M;
    const int kg  = blockIdx.y;

    for (int e = tid; e < KPG*TILE_M; e += 256) {
        int kk = e >> 6, r = e & 63;
        int nb = nbr[(size_t)(n0 + r)*KOFF + kg*KPG + kk];
        idx_lds[e] = ((unsigned)nb < (unsigned)NPTS) ? nb : 0;
    }
    __syncthreads();

    const int wave = tid >> 6;
    const int lane = tid & 63;
    const int wrow = (wave >> 1) * 32;
    const int wcol = (wave & 1) * 64;
    const int lm   = lane & 15;
    const int quad = lane >> 4;
    const int l8r  = lane >> 3;                        // row-in-8 for staging
    const int swz  = ((lane & 7) ^ l8r) << 3;          // source chunk (elements)

    f32x4 acc[2][4];
    #pragma unroll
    for (int i = 0; i < 2; ++i)
        #pragma unroll
        for (int j = 0; j < 4; ++j)
            #pragma unroll
            for (int r = 0; r < 4; ++r) acc[i][j][r] = 0.0f;

    int aoff[2][2], boff[2][4];
    #pragma unroll
    for (int kc = 0; kc < 2; ++kc) {
        int g = kc*4 + quad;
        #pragma unroll
        for (int i = 0; i < 2; ++i) {
            int row = wrow + i*16 + lm;
            aoff[kc][i] = row*128 + ((g ^ (row & 7)) << 4);
        }
        #pragma unroll
        for (int j = 0; j < 4; ++j) {
            int d = wcol + j*16 + lm;
            boff[kc][j] = d*128 + ((g ^ (d & 7)) << 4);
        }
    }

    const char* Ab = (const char*)A_lds;
    const char* Bb = (const char*)B_lds;

    for (int it = 0; it < NITER; ++it) {
        const int h  = (it >= KPG) ? 1 : 0;   // row-half OUTER (L2 working set)
        const int kk = it - h*KPG;            // k-offset inner

        // stage A (gather, 64 rows): 2 GLDS16/wave
        #pragma unroll
        for (int j = 0; j < 2; ++j) {
            int row8 = wave*16 + j*8;                  // wave-uniform
            int nb = idx_lds[kk*64 + row8 + l8r];
            GLDS16(xb + (size_t)nb*CH + h*64 + swz, &A_lds[row8*64]);
        }
        // stage B (128 rows): 4 GLDS16/wave
        const u16* wb = Wt + (size_t)(kg*KPG + kk)*CH*CH + h*64 + swz;
        #pragma unroll
        for (int j = 0; j < 4; ++j) {
            int row8 = wave*32 + j*8;
            GLDS16(wb + (size_t)(row8 + l8r)*CH, &B_lds[row8*64]);
        }
        __syncthreads();   // drain staging loads

        #pragma unroll
        for (int kc = 0; kc < 2; ++kc) {
            short8 a[2], b[4];
            #pragma unroll
            for (int i = 0; i < 2; ++i) a[i] = *(const short8*)(Ab + aoff[kc][i]);
            #pragma unroll
            for (int j = 0; j < 4; ++j) b[j] = *(const short8*)(Bb + boff[kc][j]);
            #pragma unroll
            for (int i = 0; i < 2; ++i)
                #pragma unroll
                for (int j = 0; j < 4; ++j)
                    acc[i][j] = __builtin_amdgcn_mfma_f32_16x16x32_bf16(a[i], b[j], acc[i][j], 0, 0, 0);
        }
        __syncthreads();   // all reads done before next overwrite
    }

    // epilogue: C/D layout col=lane&15, row=quad*4+reg -> bf16 partial kg
    u16* pb = part + (size_t)kg * NC;
    const int colb = wcol + lm;
    #pragma unroll
    for (int i = 0; i < 2; ++i) {
        #pragma unroll
        for (int r = 0; r < 4; ++r) {
            int row = n0 + wrow + i*16 + quad*4 + r;
            u16* pp = pb + (size_t)row*CH + colb;
            #pragma unroll
            for (int j = 0; j < 4; ++j) pp[j*16] = f2bf(acc[i][j][r]);
        }
    }
}

// ---------------------------------------------------------------------------
// sumstats: y = p0+p1+p2 (fp32 math, bf16 out to ybuf) + exact per-channel
// sum/sumsq of the SUMMED value. Vectorized: thread = 8 channels x 8 rows.
// ---------------------------------------------------------------------------
__global__ __launch_bounds__(256)
void sumstats_kernel(const u16* __restrict__ p0, const u16* __restrict__ p1,
                     const u16* __restrict__ p2, u16* __restrict__ y,
                     float* __restrict__ gsum, float* __restrict__ gsq)
{
    __shared__ float ls[CH], lq[CH];
    const int tid = threadIdx.x;
    const int c8 = (tid & 15) * 8;
    const int r0 = tid >> 4;           // 0..15
    const int b = blockIdx.x;
    if (tid < CH) { ls[tid] = 0.0f; lq[tid] = 0.0f; }
    __syncthreads();

    float s[8], q[8];
    #pragma unroll
    for (int i = 0; i < 8; ++i) { s[i] = 0.0f; q[i] = 0.0f; }

    for (int r = r0; r < 128; r += 16) {
        size_t e = (size_t)(b*128 + r)*CH + c8;
        ushort4 a0 = *(const ushort4*)(p0 + e), a1 = *(const ushort4*)(p0 + e + 4);
        ushort4 b0 = *(const ushort4*)(p1 + e), b1 = *(const ushort4*)(p1 + e + 4);
        ushort4 d0 = *(const ushort4*)(p2 + e), d1 = *(const ushort4*)(p2 + e + 4);
        float v[8];
        v[0] = bf2f(a0.x) + bf2f(b0.x) + bf2f(d0.x);
        v[1] = bf2f(a0.y) + bf2f(b0.y) + bf2f(d0.y);
        v[2] = bf2f(a0.z) + bf2f(b0.z) + bf2f(d0.z);
        v[3] = bf2f(a0.w) + bf2f(b0.w) + bf2f(d0.w);
        v[4] = bf2f(a1.x) + bf2f(b1.x) + bf2f(d1.x);
        v[5] = bf2f(a1.y) + bf2f(b1.y) + bf2f(d1.y);
        v[6] = bf2f(a1.z) + bf2f(b1.z) + bf2f(d1.z);
        v[7] = bf2f(a1.w) + bf2f(b1.w) + bf2f(d1.w);
        ushort4 o0, o1;
        o0.x = f2bf(v[0]); o0.y = f2bf(v[1]); o0.z = f2bf(v[2]); o0.w = f2bf(v[3]);
        o1.x = f2bf(v[4]); o1.y = f2bf(v[5]); o1.z = f2bf(v[6]); o1.w = f2bf(v[7]);
        *(ushort4*)(y + e) = o0;
        *(ushort4*)(y + e + 4) = o1;
        #pragma unroll
        for (int i = 0; i < 8; ++i) { s[i] += v[i]; q[i] += v[i]*v[i]; }
    }
    #pragma unroll
    for (int i = 0; i < 8; ++i) {
        atomicAdd(&ls[c8 + i], s[i]);
        atomicAdd(&lq[c8 + i], q[i]);
    }
    __syncthreads();
    if (tid < CH) {
        atomicAdd(&gsum[tid], ls[tid]);
        atomicAdd(&gsq[tid],  lq[tid]);
    }
}

// ---------------------------------------------------------------------------
// norm_relu: xo(bf16) = relu(bn(y; g,b)),  y bf16, 8 elems/thread
// ---------------------------------------------------------------------------
__global__ __launch_bounds__(256)
void norm_relu_kernel(const u16* __restrict__ y, const float* __restrict__ sums,
                      const float* __restrict__ sumsq, const float* __restrict__ gam,
                      const float* __restrict__ bet, u16* __restrict__ xo)
{
    __shared__ float sc[128], sh[128];
    const int tid = threadIdx.x;
    if (tid < 128) {
        float mu  = sums[tid] * (1.0f/NPTS);
        float var = fmaxf(sumsq[tid] * (1.0f/NPTS) - mu*mu, 0.0f);
        float rs  = rsqrtf(var + 1e-5f);
        float s   = rs * gam[tid];
        sc[tid] = s; sh[tid] = bet[tid] - mu*s;
    }
    __syncthreads();
    size_t e = ((size_t)blockIdx.x*256 + tid) * 8;
    int c0 = (int)(e & 127);
    ushort4 lo = *(const ushort4*)(y + e);
    ushort4 hi = *(const ushort4*)(y + e + 4);
    ushort4 o0, o1;
    o0.x = f2bf(fmaxf(bf2f(lo.x)*sc[c0+0] + sh[c0+0], 0.0f));
    o0.y = f2bf(fmaxf(bf2f(lo.y)*sc[c0+1] + sh[c0+1], 0.0f));
    o0.z = f2bf(fmaxf(bf2f(lo.z)*sc[c0+2] + sh[c0+2], 0.0f));
    o0.w = f2bf(fmaxf(bf2f(lo.w)*sc[c0+3] + sh[c0+3], 0.0f));
    o1.x = f2bf(fmaxf(bf2f(hi.x)*sc[c0+4] + sh[c0+4], 0.0f));
    o1.y = f2bf(fmaxf(bf2f(hi.y)*sc[c0+5] + sh[c0+5], 0.0f));
    o1.z = f2bf(fmaxf(bf2f(hi.z)*sc[c0+6] + sh[c0+6], 0.0f));
    o1.w = f2bf(fmaxf(bf2f(hi.w)*sc[c0+7] + sh[c0+7], 0.0f));
    *(ushort4*)(xo + e) = o0;
    *(ushort4*)(xo + e + 4) = o1;
}

// ---------------------------------------------------------------------------
// final: out(fp32) = relu(bn(y2; g,b) + feats)   (y2 bf16, feats/out fp32)
// ---------------------------------------------------------------------------
__global__ __launch_bounds__(256)
void final_kernel(const u16* __restrict__ y, const float* __restrict__ sums,
                  const float* __restrict__ sumsq, const float* __restrict__ gam,
                  const float* __restrict__ bet, const float* __restrict__ feats,
                  float* __restrict__ out)
{
    __shared__ float sc[128], sh[128];
    const int tid = threadIdx.x;
    if (tid < 128) {
        float mu  = sums[tid] * (1.0f/NPTS);
        float var = fmaxf(sumsq[tid] * (1.0f/NPTS) - mu*mu, 0.0f);
        float rs  = rsqrtf(var + 1e-5f);
        float s   = rs * gam[tid];
        sc[tid] = s; sh[tid] = bet[tid] - mu*s;
    }
    __syncthreads();
    size_t e = ((size_t)blockIdx.x*256 + tid) * 4;
    int c0 = (int)(e & 127);
    ushort4 in = *(const ushort4*)(y + e);
    float4 ft = *(const float4*)(feats + e);
    float4 o;
    o.x = fmaxf(bf2f(in.x)*sc[c0+0] + sh[c0+0] + ft.x, 0.0f);
    o.y = fmaxf(bf2f(in.y)*sc[c0+1] + sh[c0+1] + ft.y, 0.0f);
    o.z = fmaxf(bf2f(in.z)*sc[c0+2] + sh[c0+2] + ft.z, 0.0f);
    o.w = fmaxf(bf2f(in.w)*sc[c0+3] + sh[c0+3] + ft.w, 0.0f);
    *(float4*)(out + e) = o;
}

// ---------------------------------------------------------------------------
extern "C" void kernel_launch(void* const* d_in, const int* in_sizes, int n_in,
                              void* d_out, int out_size, void* d_ws, size_t ws_size,
                              hipStream_t stream)
{
    const float* feats = (const float*)d_in[0];
    const int*   nbr   = (const int*)d_in[1];
    const float* W1    = (const float*)d_in[2];
    const float* g1    = (const float*)d_in[3];
    const float* b1    = (const float*)d_in[4];
    const float* W2    = (const float*)d_in[5];
    const float* g2    = (const float*)d_in[6];
    const float* b2    = (const float*)d_in[7];
    float* out = (float*)d_out;

    // ws (~45.6 MB): xbuf | prt0..2 | ybuf (all bf16) | Wt1 | Wt2 | stat[512]
    char* ws = (char*)d_ws;
    u16*   xbuf = (u16*)ws;                                   // 8.4 MB
    u16*   prt  = xbuf + (size_t)NC;                          // 3 x 8.4 MB
    u16*   ybuf = prt + (size_t)3*NC;                         // 8.4 MB
    u16*   W1t  = ybuf + (size_t)NC;
    u16*   W2t  = W1t + (size_t)KOFF*CH*CH;
    float* stat = (float*)(W2t + (size_t)KOFF*CH*CH);         // s1,q1,s2,q2

    prep_kernel<<<dim3(2*KOFF + NC/2048), 256, 0, stream>>>(W1, W2, W1t, W2t, feats, xbuf, stat);

    ResidualBlock_77498389889548_kernel<<<dim3(NPTS/TILE_M, KSPLIT), 256, 0, stream>>>(
        xbuf, nbr, W1t, prt);
    sumstats_kernel<<<dim3(NPTS/128), 256, 0, stream>>>(
        prt, prt + (size_t)NC, prt + (size_t)2*NC, ybuf, stat, stat + 128);
    norm_relu_kernel<<<dim3(NC/2048), 256, 0, stream>>>(ybuf, stat, stat + 128, g1, b1, xbuf);

    ResidualBlock_77498389889548_kernel<<<dim3(NPTS/TILE_M, KSPLIT), 256, 0, stream>>>(
        xbuf, nbr, W2t, prt);
    sumstats_kernel<<<dim3(NPTS/128), 256, 0, stream>>>(
        prt, prt + (size_t)NC, prt + (size_t)2*NC, ybuf, stat + 256, stat + 384);
    final_kernel<<<dim3(NC/1024), 256, 0, stream>>>(ybuf, stat + 256, stat + 384, g2, b2, feats, out);
}